// Round 1
// baseline (62.187 us; speedup 1.0000x reference)
//
#include <hip/hip_runtime.h>
#include <math.h>

#define NB 256
#define NV 6890
#define NF 13776
#define NHD 20000
#define NPARTS 10
#define PY 120
#define PX 40
#define THREADS 512
#define NWAVES (THREADS / 64)

__device__ __forceinline__ float wred(float v) {
#pragma unroll
    for (int off = 32; off; off >>= 1) v += __shfl_down(v, off, 64);
    return v;
}

__global__ __launch_bounds__(THREADS, 1) void stab_main(
    const float* __restrict__ vertices,    // [NB, NV, 3]
    const float* __restrict__ pressure,    // [NB, PY, PX]
    const float* __restrict__ bary_w,      // [NHD, 3]
    const int*   __restrict__ faces,       // [NF, 3]
    const int*   __restrict__ face_sample, // [NHD]
    const int*   __restrict__ face_part,   // [NF]
    float* __restrict__ out,               // [1 + 512 + 512]
    float* __restrict__ ws)                // [NB] per-batch distances
{
    const int b    = blockIdx.x;
    const int tid  = threadIdx.x;
    const int wave = tid >> 6;
    const int lane = tid & 63;

    __shared__ float sv[NV * 3];           // 82680 B: full vertices[b]
    __shared__ float red[NWAVES][12];
    __shared__ float ppv[NPARTS];

    // ---- stage vertices[b] into LDS (coalesced) ----
    const float* vb = vertices + (size_t)b * (NV * 3);
    for (int i = tid; i < NV * 3; i += THREADS) sv[i] = vb[i];
    __syncthreads();

    // ---- Phase A: per-face signed tet volume -> per-part sums ----
    float pv[NPARTS];
#pragma unroll
    for (int p = 0; p < NPARTS; ++p) pv[p] = 0.0f;

    for (int f = tid; f < NF; f += THREADS) {
        const int i0 = faces[3 * f + 0];
        const int i1 = faces[3 * f + 1];
        const int i2 = faces[3 * f + 2];
        const float ax = sv[3 * i0 + 0], ay = sv[3 * i0 + 1], az = sv[3 * i0 + 2];
        const float bx = sv[3 * i1 + 0], by = sv[3 * i1 + 1], bz = sv[3 * i1 + 2];
        const float cx = sv[3 * i2 + 0], cy = sv[3 * i2 + 1], cz = sv[3 * i2 + 2];
        const float crx = by * cz - bz * cy;
        const float cry = bz * cx - bx * cz;
        const float crz = bx * cy - by * cx;
        const float tet = (ax * crx + ay * cry + az * crz) * (1.0f / 6.0f);
        const int part = face_part[f];
        // register-resident segment accumulate (avoid runtime-indexed array -> scratch)
#pragma unroll
        for (int p = 0; p < NPARTS; ++p) pv[p] += (part == p) ? tet : 0.0f;
    }
#pragma unroll
    for (int p = 0; p < NPARTS; ++p) {
        const float r = wred(pv[p]);
        if (lane == 0) red[wave][p] = r;
    }
    __syncthreads();
    if (tid < NPARTS) {
        float s = 0.0f;
#pragma unroll
        for (int w = 0; w < NWAVES; ++w) s += red[w][tid];
        ppv[tid] = s;
    }
    __syncthreads();

    // ---- Phase B: blended sample points, COM + weighted COP sums ----
    float cnx = 0.f, cny = 0.f, cd = 0.f;   // com numerator x,y ; denominator
    float pnx = 0.f, pny = 0.f, pd = 0.f;   // cop numerator x,y ; denominator
    for (int n = tid; n < NHD; n += THREADS) {
        const int fs = face_sample[n];
        const int i0 = faces[3 * fs + 0];
        const int i1 = faces[3 * fs + 1];
        const int i2 = faces[3 * fs + 2];
        const float w0 = bary_w[3 * n + 0];
        const float w1 = bary_w[3 * n + 1];
        const float w2 = bary_w[3 * n + 2];
        const float hx = w0 * sv[3 * i0 + 0] + w1 * sv[3 * i1 + 0] + w2 * sv[3 * i2 + 0];
        const float hy = w0 * sv[3 * i0 + 1] + w1 * sv[3 * i1 + 1] + w2 * sv[3 * i2 + 1];
        const float vol = ppv[face_part[fs]];
        cnx += hx * vol; cny += hy * vol; cd += vol;
        const float pw = (hy < 0.0f) ? (1.0f - 100.0f * hy) : expf(-10.0f * hy);
        pnx += hx * pw; pny += hy * pw; pd += pw;
    }

    // ---- pressure moments ----
    float pt = 0.f, pxs = 0.f, pys = 0.f;
    const float* pb = pressure + (size_t)b * (PY * PX);
    for (int i = tid; i < PY * PX; i += THREADS) {
        const float p  = pb[i];
        const float xi = (float)(i % PX);
        const float yi = (float)(i / PX);
        pt  += p;
        pxs += p * xi;
        pys += p * yi;
    }

    // ---- block reduction of the 9 scalars ----
    float vals[9] = {cnx, cny, cd, pnx, pny, pd, pt, pxs, pys};
#pragma unroll
    for (int k = 0; k < 9; ++k) {
        const float r = wred(vals[k]);
        if (lane == 0) red[wave][k] = r;
    }
    __syncthreads();

    if (tid == 0) {
        float s[9];
#pragma unroll
        for (int k = 0; k < 9; ++k) {
            float acc = 0.0f;
#pragma unroll
            for (int w = 0; w < NWAVES; ++w) acc += red[w][k];
            s[k] = acc;
        }
        const float comx = s[0] / s[2];
        const float comy = s[1] / s[2];
        const float copx = s[3] / (s[5] + 1e-6f);
        const float copy_ = s[4] / (s[5] + 1e-6f);

        // com_mat
        out[1 + 2 * b + 0] = comx * 48.0f;
        out[1 + 2 * b + 1] = (59.0f / 33.0f - comy) * 33.0f;
        // cop_mat_ipman
        out[1 + 2 * NB + 2 * b + 0] = (copx + 18.0f / 78.74f) * (100.0f * 0.7874f);
        out[1 + 2 * NB + 2 * b + 1] = (86.0f / 78.74f - copy_) * (100.0f * 0.7874f);

        // pressure CoP
        const float total = (s[6] == 0.0f) ? 1e-8f : s[6];
        const float xc = s[7] / total;
        const float yc = s[8] / total;
        const float pcopx = 0.01f * (xc - 18.0f) / 0.7874f;
        const float pcopy = 0.01f * (86.0f - yc) / 0.7874f;

        const float dx = comx - pcopx;
        const float dy = comy - pcopy;
        ws[b] = sqrtf(dx * dx + dy * dy);
    }
}

__global__ __launch_bounds__(256) void stab_reduce(const float* __restrict__ ws,
                                                   float* __restrict__ out) {
    const int tid = threadIdx.x;
    float v = ws[tid];
    v = wred(v);
    __shared__ float red[4];
    if ((tid & 63) == 0) red[tid >> 6] = v;
    __syncthreads();
    if (tid == 0) out[0] = (red[0] + red[1] + red[2] + red[3]) * (1.0f / 256.0f);
}

extern "C" void kernel_launch(void* const* d_in, const int* in_sizes, int n_in,
                              void* d_out, int out_size, void* d_ws, size_t ws_size,
                              hipStream_t stream) {
    const float* vertices    = (const float*)d_in[0];
    const float* pressure    = (const float*)d_in[1];
    const float* bary_w      = (const float*)d_in[2];
    const int*   faces       = (const int*)d_in[3];
    const int*   face_sample = (const int*)d_in[4];
    const int*   face_part   = (const int*)d_in[5];
    float* out = (float*)d_out;
    float* ws  = (float*)d_ws;

    stab_main<<<NB, THREADS, 0, stream>>>(vertices, pressure, bary_w, faces,
                                          face_sample, face_part, out, ws);
    stab_reduce<<<1, 256, 0, stream>>>(ws, out);
}

// Round 2
// 38.301 us; speedup vs baseline: 1.6237x; 1.6237x over previous
//
#include <hip/hip_runtime.h>
#include <math.h>

#define NB 256
#define NV 6890
#define NF 13776
#define NHD 20000
#define NPARTS 10
#define PY 120
#define PX 40
#define THREADS 1024
#define NWAVES (THREADS / 64)

// d_ws layout (bytes):
//   [0, 1024)                      : per-batch distances (NB floats)
//   [1024, 1024+NF*16)             : face table   int4{i0,i1,i2,part}
//   [.., +NHD*16)                  : sample table int4{i0,i1,i2,part}
//   [.., +NHD*16)                  : sample bary  float4{w0,w1,w2,0}
#define WS_DIST_OFF  0
#define WS_TABF_OFF  1024
#define WS_TABS_OFF  (WS_TABF_OFF + NF * 16)
#define WS_TABW_OFF  (WS_TABS_OFF + NHD * 16)
#define WS_NEEDED    (WS_TABW_OFF + NHD * 16)

__device__ __forceinline__ float wred(float v) {
#pragma unroll
    for (int off = 32; off; off >>= 1) v += __shfl_down(v, off, 64);
    return v;
}

__global__ __launch_bounds__(256) void build_face_tab(const int* __restrict__ faces,
                                                      const int* __restrict__ face_part,
                                                      int4* __restrict__ tabF) {
    const int f = blockIdx.x * 256 + threadIdx.x;
    if (f < NF)
        tabF[f] = make_int4(faces[3 * f + 0], faces[3 * f + 1], faces[3 * f + 2], face_part[f]);
}

__global__ __launch_bounds__(256) void build_samp_tab(const int* __restrict__ faces,
                                                      const int* __restrict__ face_sample,
                                                      const int* __restrict__ face_part,
                                                      const float* __restrict__ bary_w,
                                                      int4* __restrict__ tabS,
                                                      float4* __restrict__ tabW) {
    const int n = blockIdx.x * 256 + threadIdx.x;
    if (n < NHD) {
        const int fs = face_sample[n];
        tabS[n] = make_int4(faces[3 * fs + 0], faces[3 * fs + 1], faces[3 * fs + 2], face_part[fs]);
        tabW[n] = make_float4(bary_w[3 * n + 0], bary_w[3 * n + 1], bary_w[3 * n + 2], 0.0f);
    }
}

template <bool TAB>
__global__ __launch_bounds__(THREADS, 4) void stab_main(
    const float* __restrict__ vertices,    // [NB, NV, 3]
    const float* __restrict__ pressure,    // [NB, PY, PX]
    const float* __restrict__ bary_w,      // [NHD, 3]
    const int*   __restrict__ faces,       // [NF, 3]
    const int*   __restrict__ face_sample, // [NHD]
    const int*   __restrict__ face_part,   // [NF]
    const int4*  __restrict__ tabF,        // [NF]  (TAB path)
    const int4*  __restrict__ tabS,        // [NHD] (TAB path)
    const float4* __restrict__ tabW,       // [NHD] (TAB path)
    float* __restrict__ out,               // [1 + 512 + 512]
    float* __restrict__ dist)              // [NB]
{
    const int b    = blockIdx.x;
    const int tid  = threadIdx.x;
    const int wave = tid >> 6;
    const int lane = tid & 63;

    __shared__ float2 svxy[NV];            // 55120 B
    __shared__ float  svz[NV];             // 27560 B
    __shared__ float  red[NWAVES][12];
    __shared__ float  ppv[NPARTS];

    // ---- stage vertices[b] into LDS, split xy / z ----
    const float* vb = vertices + (size_t)b * (NV * 3);
    for (int v = tid; v < NV; v += THREADS) {
        const float x = vb[3 * v + 0];
        const float y = vb[3 * v + 1];
        const float z = vb[3 * v + 2];
        svxy[v] = make_float2(x, y);
        svz[v]  = z;
    }
    __syncthreads();

    // ---- Phase A: per-face signed tet volume -> per-part sums ----
    float pv[NPARTS];
#pragma unroll
    for (int p = 0; p < NPARTS; ++p) pv[p] = 0.0f;

    for (int f = tid; f < NF; f += THREADS) {
        int i0, i1, i2, part;
        if constexpr (TAB) {
            const int4 q = tabF[f];
            i0 = q.x; i1 = q.y; i2 = q.z; part = q.w;
        } else {
            i0 = faces[3 * f + 0]; i1 = faces[3 * f + 1]; i2 = faces[3 * f + 2];
            part = face_part[f];
        }
        const float2 a = svxy[i0]; const float az = svz[i0];
        const float2 bb = svxy[i1]; const float bz = svz[i1];
        const float2 cc = svxy[i2]; const float cz = svz[i2];
        const float crx = bb.y * cz - bz * cc.y;
        const float cry = bz * cc.x - bb.x * cz;
        const float crz = bb.x * cc.y - bb.y * cc.x;
        const float tet = (a.x * crx + a.y * cry + az * crz) * (1.0f / 6.0f);
#pragma unroll
        for (int p = 0; p < NPARTS; ++p) pv[p] += (part == p) ? tet : 0.0f;
    }
#pragma unroll
    for (int p = 0; p < NPARTS; ++p) {
        const float r = wred(pv[p]);
        if (lane == 0) red[wave][p] = r;
    }
    __syncthreads();
    if (tid < NPARTS) {
        float s = 0.0f;
#pragma unroll
        for (int w = 0; w < NWAVES; ++w) s += red[w][tid];
        ppv[tid] = s;
    }
    __syncthreads();

    // ---- Phase B: blended samples -> COM + weighted-CoP sums ----
    float cnx = 0.f, cny = 0.f, cd = 0.f;
    float pnx = 0.f, pny = 0.f, pd = 0.f;
    for (int n = tid; n < NHD; n += THREADS) {
        int i0, i1, i2, part;
        float w0, w1, w2;
        if constexpr (TAB) {
            const int4 q = tabS[n];
            const float4 w = tabW[n];
            i0 = q.x; i1 = q.y; i2 = q.z; part = q.w;
            w0 = w.x; w1 = w.y; w2 = w.z;
        } else {
            const int fs = face_sample[n];
            i0 = faces[3 * fs + 0]; i1 = faces[3 * fs + 1]; i2 = faces[3 * fs + 2];
            part = face_part[fs];
            w0 = bary_w[3 * n + 0]; w1 = bary_w[3 * n + 1]; w2 = bary_w[3 * n + 2];
        }
        const float2 p0 = svxy[i0];
        const float2 p1 = svxy[i1];
        const float2 p2 = svxy[i2];
        const float hx = w0 * p0.x + w1 * p1.x + w2 * p2.x;
        const float hy = w0 * p0.y + w1 * p1.y + w2 * p2.y;
        const float vol = ppv[part];
        cnx += hx * vol; cny += hy * vol; cd += vol;
        const float pw = (hy < 0.0f) ? (1.0f - 100.0f * hy) : __expf(-10.0f * hy);
        pnx += hx * pw; pny += hy * pw; pd += pw;
    }

    // ---- pressure moments ----
    float pt = 0.f, pxs = 0.f, pys = 0.f;
    const float* pb = pressure + (size_t)b * (PY * PX);
    for (int i = tid; i < PY * PX; i += THREADS) {
        const float p  = pb[i];
        const float xi = (float)(i % PX);
        const float yi = (float)(i / PX);
        pt  += p;
        pxs += p * xi;
        pys += p * yi;
    }

    // ---- block reduction of 9 scalars ----
    float vals[9] = {cnx, cny, cd, pnx, pny, pd, pt, pxs, pys};
#pragma unroll
    for (int k = 0; k < 9; ++k) {
        const float r = wred(vals[k]);
        if (lane == 0) red[wave][k] = r;
    }
    __syncthreads();

    if (tid == 0) {
        float s[9];
#pragma unroll
        for (int k = 0; k < 9; ++k) {
            float acc = 0.0f;
#pragma unroll
            for (int w = 0; w < NWAVES; ++w) acc += red[w][k];
            s[k] = acc;
        }
        const float comx  = s[0] / s[2];
        const float comy  = s[1] / s[2];
        const float copx  = s[3] / (s[5] + 1e-6f);
        const float copy_ = s[4] / (s[5] + 1e-6f);

        out[1 + 2 * b + 0] = comx * 48.0f;
        out[1 + 2 * b + 1] = (59.0f / 33.0f - comy) * 33.0f;
        out[1 + 2 * NB + 2 * b + 0] = (copx + 18.0f / 78.74f) * (100.0f * 0.7874f);
        out[1 + 2 * NB + 2 * b + 1] = (86.0f / 78.74f - copy_) * (100.0f * 0.7874f);

        const float total = (s[6] == 0.0f) ? 1e-8f : s[6];
        const float xc = s[7] / total;
        const float yc = s[8] / total;
        const float pcopx = 0.01f * (xc - 18.0f) / 0.7874f;
        const float pcopy = 0.01f * (86.0f - yc) / 0.7874f;

        const float dx = comx - pcopx;
        const float dy = comy - pcopy;
        dist[b] = sqrtf(dx * dx + dy * dy);
    }
}

__global__ __launch_bounds__(256) void stab_reduce(const float* __restrict__ dist,
                                                   float* __restrict__ out) {
    const int tid = threadIdx.x;
    float v = dist[tid];
    v = wred(v);
    __shared__ float red[4];
    if ((tid & 63) == 0) red[tid >> 6] = v;
    __syncthreads();
    if (tid == 0) out[0] = (red[0] + red[1] + red[2] + red[3]) * (1.0f / 256.0f);
}

extern "C" void kernel_launch(void* const* d_in, const int* in_sizes, int n_in,
                              void* d_out, int out_size, void* d_ws, size_t ws_size,
                              hipStream_t stream) {
    const float* vertices    = (const float*)d_in[0];
    const float* pressure    = (const float*)d_in[1];
    const float* bary_w      = (const float*)d_in[2];
    const int*   faces       = (const int*)d_in[3];
    const int*   face_sample = (const int*)d_in[4];
    const int*   face_part   = (const int*)d_in[5];
    float* out = (float*)d_out;
    char*  ws  = (char*)d_ws;

    float* dist = (float*)(ws + WS_DIST_OFF);

    if (ws_size >= (size_t)WS_NEEDED) {
        int4*   tabF = (int4*)(ws + WS_TABF_OFF);
        int4*   tabS = (int4*)(ws + WS_TABS_OFF);
        float4* tabW = (float4*)(ws + WS_TABW_OFF);
        build_face_tab<<<(NF + 255) / 256, 256, 0, stream>>>(faces, face_part, tabF);
        build_samp_tab<<<(NHD + 255) / 256, 256, 0, stream>>>(faces, face_sample, face_part,
                                                              bary_w, tabS, tabW);
        stab_main<true><<<NB, THREADS, 0, stream>>>(vertices, pressure, bary_w, faces,
                                                    face_sample, face_part, tabF, tabS, tabW,
                                                    out, dist);
    } else {
        stab_main<false><<<NB, THREADS, 0, stream>>>(vertices, pressure, bary_w, faces,
                                                     face_sample, face_part, nullptr, nullptr,
                                                     nullptr, out, dist);
    }
    stab_reduce<<<1, 256, 0, stream>>>(dist, out);
}

// Round 3
// 37.233 us; speedup vs baseline: 1.6702x; 1.0287x over previous
//
#include <hip/hip_runtime.h>
#include <math.h>

#define NB 256
#define NV 6890
#define NF 13776
#define NHD 20000
#define NPARTS 10
#define PY 120
#define PX 40
#define THREADS 1024
#define NWAVES (THREADS / 64)

// d_ws layout (bytes):
//   [0, 1024)            : per-batch distances (NB floats)
//   [1024, +NF*16)       : face table   int4{i0,i1,i2,part}
//   [.., +NHD*16)        : sample table int4{i0,i1,i2,part}
//   [.., +NHD*16)        : sample bary  float4{w0,w1,w2,0}
#define WS_DIST_OFF  0
#define WS_TABF_OFF  1024
#define WS_TABS_OFF  (WS_TABF_OFF + NF * 16)
#define WS_TABW_OFF  (WS_TABS_OFF + NHD * 16)
#define WS_NEEDED    (WS_TABW_OFF + NHD * 16)

__device__ __forceinline__ float wred(float v) {
#pragma unroll
    for (int off = 32; off; off >>= 1) v += __shfl_down(v, off, 64);
    return v;
}

__global__ __launch_bounds__(256) void build_tabs(const int* __restrict__ faces,
                                                  const int* __restrict__ face_part,
                                                  const int* __restrict__ face_sample,
                                                  const float* __restrict__ bary_w,
                                                  int4* __restrict__ tabF,
                                                  int4* __restrict__ tabS,
                                                  float4* __restrict__ tabW) {
    const int i = blockIdx.x * 256 + threadIdx.x;
    if (i < NF)
        tabF[i] = make_int4(faces[3 * i + 0], faces[3 * i + 1], faces[3 * i + 2], face_part[i]);
    if (i < NHD) {
        const int fs = face_sample[i];
        tabS[i] = make_int4(faces[3 * fs + 0], faces[3 * fs + 1], faces[3 * fs + 2], face_part[fs]);
        tabW[i] = make_float4(bary_w[3 * i + 0], bary_w[3 * i + 1], bary_w[3 * i + 2], 0.0f);
    }
}

__device__ __forceinline__ float tet_of(const float* __restrict__ svx,
                                        const float* __restrict__ svy,
                                        const float* __restrict__ svz, int4 q) {
    const float ax = svx[q.x], bx = svx[q.y], cx = svx[q.z];
    const float ay = svy[q.x], by = svy[q.y], cy = svy[q.z];
    const float az = svz[q.x], bz = svz[q.y], cz = svz[q.z];
    return (ax * (by * cz - bz * cy) + ay * (bz * cx - bx * cz) + az * (bx * cy - by * cx)) *
           (1.0f / 6.0f);
}

template <bool TAB>
__global__ __launch_bounds__(THREADS, 4) void stab_main(
    const float* __restrict__ vertices,    // [NB, NV, 3]
    const float* __restrict__ pressure,    // [NB, PY, PX]
    const float* __restrict__ bary_w,      // [NHD, 3]
    const int*   __restrict__ faces,       // [NF, 3]
    const int*   __restrict__ face_sample, // [NHD]
    const int*   __restrict__ face_part,   // [NF]
    const int4*  __restrict__ tabF,        // [NF]
    const int4*  __restrict__ tabS,        // [NHD]
    const float4* __restrict__ tabW,       // [NHD]
    float* __restrict__ out,
    float* __restrict__ dist)
{
    const int b    = blockIdx.x;
    const int tid  = threadIdx.x;
    const int wave = tid >> 6;
    const int lane = tid & 63;

    __shared__ float svx[NV];
    __shared__ float svy[NV];
    __shared__ float svz[NV];
    __shared__ float red[NWAVES][12];
    __shared__ float ppv[NPARTS];

    // ---- stage vertices[b] into LDS (SoA: b32 gathers spread all 32 banks) ----
    const float* vb = vertices + (size_t)b * (NV * 3);
    for (int v = tid; v < NV; v += THREADS) {
        svx[v] = vb[3 * v + 0];
        svy[v] = vb[3 * v + 1];
        svz[v] = vb[3 * v + 2];
    }
    __syncthreads();

    // ---- Phase A: tet volumes -> per-part sums (4 independent chains / iter) ----
    float pv[NPARTS];
#pragma unroll
    for (int p = 0; p < NPARTS; ++p) pv[p] = 0.0f;

    if constexpr (TAB) {
        for (int f0 = tid; f0 < NF; f0 += 4 * THREADS) {
            const int f1 = f0 + THREADS, f2 = f0 + 2 * THREADS, f3 = f0 + 3 * THREADS;
            const int g1 = min(f1, NF - 1), g2 = min(f2, NF - 1), g3 = min(f3, NF - 1);
            const int4 q0 = tabF[f0];
            const int4 q1 = tabF[g1];
            const int4 q2 = tabF[g2];
            const int4 q3 = tabF[g3];
            const float m1 = (f1 < NF) ? 1.0f : 0.0f;
            const float m2 = (f2 < NF) ? 1.0f : 0.0f;
            const float m3 = (f3 < NF) ? 1.0f : 0.0f;
            const float t0 = tet_of(svx, svy, svz, q0);
            const float t1 = tet_of(svx, svy, svz, q1) * m1;
            const float t2 = tet_of(svx, svy, svz, q2) * m2;
            const float t3 = tet_of(svx, svy, svz, q3) * m3;
#pragma unroll
            for (int p = 0; p < NPARTS; ++p) {
                pv[p] += (q0.w == p) ? t0 : 0.0f;
                pv[p] += (q1.w == p) ? t1 : 0.0f;
                pv[p] += (q2.w == p) ? t2 : 0.0f;
                pv[p] += (q3.w == p) ? t3 : 0.0f;
            }
        }
    } else {
        for (int f = tid; f < NF; f += THREADS) {
            const int4 q = make_int4(faces[3 * f + 0], faces[3 * f + 1], faces[3 * f + 2],
                                     face_part[f]);
            const float t = tet_of(svx, svy, svz, q);
#pragma unroll
            for (int p = 0; p < NPARTS; ++p) pv[p] += (q.w == p) ? t : 0.0f;
        }
    }
#pragma unroll
    for (int p = 0; p < NPARTS; ++p) {
        const float r = wred(pv[p]);
        if (lane == 0) red[wave][p] = r;
    }
    __syncthreads();
    if (tid < NPARTS) {
        float s = 0.0f;
#pragma unroll
        for (int w = 0; w < NWAVES; ++w) s += red[w][tid];
        ppv[tid] = s;
    }
    __syncthreads();

    // ---- Phase B: blended samples (4 independent chains / iter) ----
    float cnx = 0.f, cny = 0.f, cd = 0.f;
    float pnx = 0.f, pny = 0.f, pd = 0.f;

    if constexpr (TAB) {
        for (int n0 = tid; n0 < NHD; n0 += 4 * THREADS) {
            const int n1 = n0 + THREADS, n2 = n0 + 2 * THREADS, n3 = n0 + 3 * THREADS;
            const int h1 = min(n1, NHD - 1), h2 = min(n2, NHD - 1), h3 = min(n3, NHD - 1);
            const int4 q0 = tabS[n0];
            const int4 q1 = tabS[h1];
            const int4 q2 = tabS[h2];
            const int4 q3 = tabS[h3];
            const float4 w0 = tabW[n0];
            const float4 w1 = tabW[h1];
            const float4 w2 = tabW[h2];
            const float4 w3 = tabW[h3];
            const float m1 = (n1 < NHD) ? 1.0f : 0.0f;
            const float m2 = (n2 < NHD) ? 1.0f : 0.0f;
            const float m3 = (n3 < NHD) ? 1.0f : 0.0f;

            const float hx0 = w0.x * svx[q0.x] + w0.y * svx[q0.y] + w0.z * svx[q0.z];
            const float hy0 = w0.x * svy[q0.x] + w0.y * svy[q0.y] + w0.z * svy[q0.z];
            const float hx1 = w1.x * svx[q1.x] + w1.y * svx[q1.y] + w1.z * svx[q1.z];
            const float hy1 = w1.x * svy[q1.x] + w1.y * svy[q1.y] + w1.z * svy[q1.z];
            const float hx2 = w2.x * svx[q2.x] + w2.y * svx[q2.y] + w2.z * svx[q2.z];
            const float hy2 = w2.x * svy[q2.x] + w2.y * svy[q2.y] + w2.z * svy[q2.z];
            const float hx3 = w3.x * svx[q3.x] + w3.y * svx[q3.y] + w3.z * svx[q3.z];
            const float hy3 = w3.x * svy[q3.x] + w3.y * svy[q3.y] + w3.z * svy[q3.z];

            const float vol0 = ppv[q0.w];
            const float vol1 = ppv[q1.w] * m1;
            const float vol2 = ppv[q2.w] * m2;
            const float vol3 = ppv[q3.w] * m3;

            const float pw0 = ((hy0 < 0.0f) ? (1.0f - 100.0f * hy0) : __expf(-10.0f * hy0));
            const float pw1 = ((hy1 < 0.0f) ? (1.0f - 100.0f * hy1) : __expf(-10.0f * hy1)) * m1;
            const float pw2 = ((hy2 < 0.0f) ? (1.0f - 100.0f * hy2) : __expf(-10.0f * hy2)) * m2;
            const float pw3 = ((hy3 < 0.0f) ? (1.0f - 100.0f * hy3) : __expf(-10.0f * hy3)) * m3;

            cnx += hx0 * vol0 + hx1 * vol1 + hx2 * vol2 + hx3 * vol3;
            cny += hy0 * vol0 + hy1 * vol1 + hy2 * vol2 + hy3 * vol3;
            cd  += vol0 + vol1 + vol2 + vol3;
            pnx += hx0 * pw0 + hx1 * pw1 + hx2 * pw2 + hx3 * pw3;
            pny += hy0 * pw0 + hy1 * pw1 + hy2 * pw2 + hy3 * pw3;
            pd  += pw0 + pw1 + pw2 + pw3;
        }
    } else {
        for (int n = tid; n < NHD; n += THREADS) {
            const int fs = face_sample[n];
            const int i0 = faces[3 * fs + 0], i1 = faces[3 * fs + 1], i2 = faces[3 * fs + 2];
            const float w0 = bary_w[3 * n + 0], w1 = bary_w[3 * n + 1], w2 = bary_w[3 * n + 2];
            const float hx = w0 * svx[i0] + w1 * svx[i1] + w2 * svx[i2];
            const float hy = w0 * svy[i0] + w1 * svy[i1] + w2 * svy[i2];
            const float vol = ppv[face_part[fs]];
            cnx += hx * vol; cny += hy * vol; cd += vol;
            const float pw = (hy < 0.0f) ? (1.0f - 100.0f * hy) : __expf(-10.0f * hy);
            pnx += hx * pw; pny += hy * pw; pd += pw;
        }
    }

    // ---- pressure moments ----
    float pt = 0.f, pxs = 0.f, pys = 0.f;
    const float* pb = pressure + (size_t)b * (PY * PX);
    for (int i = tid; i < PY * PX; i += THREADS) {
        const float p  = pb[i];
        const float xi = (float)(i % PX);
        const float yi = (float)(i / PX);
        pt  += p;
        pxs += p * xi;
        pys += p * yi;
    }

    // ---- block reduction of 9 scalars ----
    float vals[9] = {cnx, cny, cd, pnx, pny, pd, pt, pxs, pys};
#pragma unroll
    for (int k = 0; k < 9; ++k) {
        const float r = wred(vals[k]);
        if (lane == 0) red[wave][k] = r;
    }
    __syncthreads();

    if (tid == 0) {
        float s[9];
#pragma unroll
        for (int k = 0; k < 9; ++k) {
            float acc = 0.0f;
#pragma unroll
            for (int w = 0; w < NWAVES; ++w) acc += red[w][k];
            s[k] = acc;
        }
        const float comx  = s[0] / s[2];
        const float comy  = s[1] / s[2];
        const float copx  = s[3] / (s[5] + 1e-6f);
        const float copy_ = s[4] / (s[5] + 1e-6f);

        out[1 + 2 * b + 0] = comx * 48.0f;
        out[1 + 2 * b + 1] = (59.0f / 33.0f - comy) * 33.0f;
        out[1 + 2 * NB + 2 * b + 0] = (copx + 18.0f / 78.74f) * (100.0f * 0.7874f);
        out[1 + 2 * NB + 2 * b + 1] = (86.0f / 78.74f - copy_) * (100.0f * 0.7874f);

        const float total = (s[6] == 0.0f) ? 1e-8f : s[6];
        const float xc = s[7] / total;
        const float yc = s[8] / total;
        const float pcopx = 0.01f * (xc - 18.0f) / 0.7874f;
        const float pcopy = 0.01f * (86.0f - yc) / 0.7874f;

        const float dx = comx - pcopx;
        const float dy = comy - pcopy;
        dist[b] = sqrtf(dx * dx + dy * dy);
    }
}

__global__ __launch_bounds__(256) void stab_reduce(const float* __restrict__ dist,
                                                   float* __restrict__ out) {
    const int tid = threadIdx.x;
    float v = dist[tid];
    v = wred(v);
    __shared__ float red[4];
    if ((tid & 63) == 0) red[tid >> 6] = v;
    __syncthreads();
    if (tid == 0) out[0] = (red[0] + red[1] + red[2] + red[3]) * (1.0f / 256.0f);
}

extern "C" void kernel_launch(void* const* d_in, const int* in_sizes, int n_in,
                              void* d_out, int out_size, void* d_ws, size_t ws_size,
                              hipStream_t stream) {
    const float* vertices    = (const float*)d_in[0];
    const float* pressure    = (const float*)d_in[1];
    const float* bary_w      = (const float*)d_in[2];
    const int*   faces       = (const int*)d_in[3];
    const int*   face_sample = (const int*)d_in[4];
    const int*   face_part   = (const int*)d_in[5];
    float* out = (float*)d_out;
    char*  ws  = (char*)d_ws;

    float* dist = (float*)(ws + WS_DIST_OFF);

    if (ws_size >= (size_t)WS_NEEDED) {
        int4*   tabF = (int4*)(ws + WS_TABF_OFF);
        int4*   tabS = (int4*)(ws + WS_TABS_OFF);
        float4* tabW = (float4*)(ws + WS_TABW_OFF);
        build_tabs<<<(NHD + 255) / 256, 256, 0, stream>>>(faces, face_part, face_sample,
                                                          bary_w, tabF, tabS, tabW);
        stab_main<true><<<NB, THREADS, 0, stream>>>(vertices, pressure, bary_w, faces,
                                                    face_sample, face_part, tabF, tabS, tabW,
                                                    out, dist);
    } else {
        stab_main<false><<<NB, THREADS, 0, stream>>>(vertices, pressure, bary_w, faces,
                                                     face_sample, face_part, nullptr, nullptr,
                                                     nullptr, out, dist);
    }
    stab_reduce<<<1, 256, 0, stream>>>(dist, out);
}